// Round 1
// 97.901 us; speedup vs baseline: 1.0263x; 1.0263x over previous
//
#include <hip/hip_runtime.h>

#define BC 4
#define HD 1025
#define WD 1024
#define HCH 16      // outputs per lane, harm (one wave per full row)
#define PCH 8       // outputs per thread, perc
#define REG 1056    // floats per wave-private LDS region in harm: [-16, 1040)

__device__ __forceinline__ void ce(float& x, float& y) {
    float lo = fminf(x, y);
    float hi = fmaxf(x, y);
    x = lo; y = hi;
}

// Knuth 5.2.2M merge-exchange sorting network; valid for any N <= 2^T.
template<int N, int T>
__device__ __forceinline__ void sortN(float* a) {
#pragma unroll
    for (int pk = T - 1; pk >= 0; --pk) {
        const int p = 1 << pk;
#pragma unroll
        for (int k = 0; k <= T - 1 - pk; ++k) {
            const int d = (k == 0) ? p : (((1 << (T - 1)) >> (k - 1)) - p);
            const int r = (k == 0) ? 0 : p;
#pragma unroll
            for (int i = 0; i < N - d; ++i)
                if ((i & p) == r) ce(a[i], a[i + d]);
        }
    }
}

// Sorted sliding update on the 7-element "moving part".
// Remove oldv (monotone predicate), insert newv via med3 chain. ~19 VALU.
__device__ __forceinline__ void slide7(float* M, float oldv, float newv) {
    float r0 = (M[0] >= oldv) ? M[1] : M[0];
    float r1 = (M[1] >= oldv) ? M[2] : M[1];
    float r2 = (M[2] >= oldv) ? M[3] : M[2];
    float r3 = (M[3] >= oldv) ? M[4] : M[3];
    float r4 = (M[4] >= oldv) ? M[5] : M[4];
    float r5 = (M[5] >= oldv) ? M[6] : M[5];
    M[0] = fminf(r0, newv);
    M[1] = __builtin_amdgcn_fmed3f(newv, r0, r1);
    M[2] = __builtin_amdgcn_fmed3f(newv, r1, r2);
    M[3] = __builtin_amdgcn_fmed3f(newv, r2, r3);
    M[4] = __builtin_amdgcn_fmed3f(newv, r3, r4);
    M[5] = fmaxf(r5, newv) == r5 ? __builtin_amdgcn_fmed3f(newv, r4, r5) : __builtin_amdgcn_fmed3f(newv, r4, r5);
    M[6] = fmaxf(r5, newv);
}

// rank-16 (median of 31) of sorted C[0..23] ∪ sorted M[0..6]:
// min over i of max(C[i-1], M[15-i]), i in [9..16].  15 VALU, depth 4.
__device__ __forceinline__ float sel16(const float* C, const float* M) {
    float c0 = fmaxf(C[8],  M[6]);
    float c1 = fmaxf(C[9],  M[5]);
    float c2 = fmaxf(C[10], M[4]);
    float c3 = fmaxf(C[11], M[3]);
    float c4 = fmaxf(C[12], M[2]);
    float c5 = fmaxf(C[13], M[1]);
    float c6 = fmaxf(C[14], M[0]);
    float c7 = C[15];
    float t0 = fminf(c0, c1), t1 = fminf(c2, c3);
    float t2 = fminf(c4, c5), t3 = fminf(c6, c7);
    return fminf(fminf(t0, t1), fminf(t2, t3));
}

// XOR swizzle on 16B units: makes both coalesced (unit=lane+64*it) and
// lane-private (unit=4*lane+k) b128 access hit the structural-minimum 8 phases.
__device__ __forceinline__ float* swz(float* base, int f /* float idx, %4==0 */) {
    int u = f >> 2;
    u ^= (u >> 3) & 7;
    return base + (u << 2);
}

// Median along W. One wave per row (1024 outputs, 16/lane), wave-private LDS
// segment, NO block barriers (span preloaded to regs before any LDS reuse).
// Compute: two chunks of 8 outputs; each chunk = sorted 24-core (shared) +
// sliding sorted 7-list + 2-array rank selection.
__global__ __launch_bounds__(256, 4) void harm_kernel(const float* __restrict__ S,
                                                      float* __restrict__ harm) {
    __shared__ float lds[4 * REG];
    const int tid = threadIdx.x;
    const int wv = tid >> 6, ln = tid & 63;
    const int row = blockIdx.x * 4 + wv;
    const int plane = blockIdx.z;
    const bool rowok = (row < HD);
    float* wl = lds + wv * REG;
    const float* rowg = S + ((size_t)plane * HD + row) * WD;

    if (rowok) {
        // stage floats for w in [-16, 1040): region idx t = w + 16
#pragma unroll
        for (int it = 0; it < 5; ++it) {
            int t = 4 * ln + 256 * it;
            if (t < REG) {
                int g = t - 16;
                float4 v;
                if (g >= 0 && g + 3 < WD) {
                    v = *(const float4*)(rowg + g);
                } else {
                    v.x = ((unsigned)(g + 0) < WD) ? rowg[g + 0] : 0.f;
                    v.y = ((unsigned)(g + 1) < WD) ? rowg[g + 1] : 0.f;
                    v.z = ((unsigned)(g + 2) < WD) ? rowg[g + 2] : 0.f;
                    v.w = ((unsigned)(g + 3) < WD) ? rowg[g + 3] : 0.f;
                }
                *(float4*)swz(wl, t) = v;
            }
        }
    }
    __builtin_amdgcn_wave_barrier();

    float m[HCH];
    if (rowok) {
        // preload full span to registers: w in [w0-16, w0+32), w0 = 16*ln
        float raw[48];
#pragma unroll
        for (int k = 0; k < 12; ++k) {
            float4 v = *(const float4*)swz(wl, 16 * ln + 4 * k);
            raw[4 * k + 0] = v.x; raw[4 * k + 1] = v.y;
            raw[4 * k + 2] = v.z; raw[4 * k + 3] = v.w;
        }
        // window for output s (0..15) is raw[s+1 .. s+31]
#pragma unroll
        for (int c = 0; c < 2; ++c) {
            float C[24];
#pragma unroll
            for (int j = 0; j < 24; ++j) C[j] = raw[8 * c + 8 + j];
            sortN<24, 5>(C);          // only C[8..15] consumed -> tail CEs DCE'd
            float M[7];
#pragma unroll
            for (int j = 0; j < 7; ++j) M[j] = raw[8 * c + 1 + j];
            sortN<7, 3>(M);
            m[8 * c] = sel16(C, M);
#pragma unroll
            for (int s = 1; s < 8; ++s) {
                slide7(M, raw[8 * c + s], raw[8 * c + 31 + s]);
                m[8 * c + s] = sel16(C, M);
            }
        }
    }
    __builtin_amdgcn_wave_barrier();   // input region dead (raw in regs) -> reuse
    if (rowok) {
#pragma unroll
        for (int g = 0; g < 4; ++g)
            *(float4*)swz(wl, 16 * ln + 4 * g) =
                make_float4(m[4 * g + 0], m[4 * g + 1], m[4 * g + 2], m[4 * g + 3]);
    }
    __builtin_amdgcn_wave_barrier();
    if (rowok) {
        float* hrow = harm + ((size_t)plane * HD + row) * WD;
#pragma unroll
        for (int it = 0; it < 4; ++it) {
            int t = 4 * ln + 256 * it;
            *(float4*)(hrow + t) = *(const float4*)swz(wl, t);
        }
    }
}

// Median along H + fused softmask. Span of 38 rows preloaded to registers
// (coalesced, lane = w); compute = sorted 24-core + sliding 7-list + select.
__global__ __launch_bounds__(256, 4) void perc_mask_kernel(const float* __restrict__ S,
                                                           const float* __restrict__ harm,
                                                           float* __restrict__ out0,
                                                           float* __restrict__ out1) {
    const int w = blockIdx.x * 256 + threadIdx.x;   // 0..1023
    const int h0 = blockIdx.y * PCH;
    const int plane = blockIdx.z;
    const size_t poff = (size_t)plane * HD * WD;
    const float* base = S + poff;

    float span[38];                                  // rows h0-15 .. h0+22
#pragma unroll
    for (int j = 0; j < 38; ++j) {
        int h = h0 - 15 + j;
        span[j] = ((unsigned)h < (unsigned)HD) ? base[(size_t)h * WD + w] : 0.f;
    }

    // window for output s (0..7) is span[s .. s+30]; core = span[7..30]
    float C[24];
#pragma unroll
    for (int j = 0; j < 24; ++j) C[j] = span[7 + j];
    sortN<24, 5>(C);
    float M[7];
#pragma unroll
    for (int j = 0; j < 7; ++j) M[j] = span[j];
    sortN<7, 3>(M);

#pragma unroll
    for (int s = 0; s < PCH; ++s) {
        int h = h0 + s;
        if (h >= HD) break;                          // block-uniform
        if (s > 0) slide7(M, span[s - 1], span[s + 30]);
        float pm = sel16(C, M);
        float sv = span[15 + s];
        size_t idx = poff + (size_t)h * WD + w;
        float hmv = harm[idx];
        float h2 = hmv * hmv;
        float p2 = pm * pm;
        float inv = 1.0f / (h2 + p2);
        out0[idx] = sv * h2 * inv;
        out1[idx] = sv * p2 * inv;
    }
}

extern "C" void kernel_launch(void* const* d_in, const int* in_sizes, int n_in,
                              void* d_out, int out_size, void* d_ws, size_t ws_size,
                              hipStream_t stream) {
    const float* S = (const float*)d_in[0];
    float* out = (float*)d_out;
    const size_t N = (size_t)BC * HD * WD;  // 4,198,400
    float* harm = out;          // phase-1 scratch, overwritten by out0 in phase 2
    float* out1 = out + N;

    dim3 hgrid((HD + 3) / 4, 1, BC);                   // (257, 1, 4)
    harm_kernel<<<hgrid, 256, 0, stream>>>(S, harm);

    dim3 pgrid(WD / 256, (HD + PCH - 1) / PCH, BC);    // (4, 129, 4)
    perc_mask_kernel<<<pgrid, 256, 0, stream>>>(S, harm, out, out1);
}